// Round 1
// baseline (6154.960 us; speedup 1.0000x reference)
//
#include <hip/hip_runtime.h>
#include <math.h>

#define H 128
#define OUTD 40
#define BN_EPS 1e-5f
#define NEG_SLOPE 0.01f

__device__ __forceinline__ float4 ld4(const float* p) {
    return *reinterpret_cast<const float4*>(p);
}

// ---------------- scatter: agg[dst] += x[src], deg[dst] += 1 ----------------
__global__ __launch_bounds__(256) void k_scatter1(
    const float* __restrict__ x, const int* __restrict__ src, const int* __restrict__ dst,
    float* __restrict__ agg, float* __restrict__ deg, long long total)
{
    long long t = (long long)blockIdx.x * blockDim.x + threadIdx.x;
    if (t >= total) return;
    int e = (int)(t >> 5);
    int q = (int)(t & 31);
    int s = src[e], d = dst[e];
    float4 v = ld4(x + (size_t)s * H + q * 4);
    float* ap = agg + (size_t)d * H + q * 4;
    atomicAdd(ap + 0, v.x); atomicAdd(ap + 1, v.y);
    atomicAdd(ap + 2, v.z); atomicAdd(ap + 3, v.w);
    if (q == 0) atomicAdd(deg + d, 1.0f);
}

// -------- scatter2: agg[dst] += relu(affine1(h[src]))  (BN1 applied on read) --------
__global__ __launch_bounds__(256) void k_scatter2(
    const float* __restrict__ h, const float* __restrict__ scale, const float* __restrict__ shift,
    const int* __restrict__ src, const int* __restrict__ dst,
    float* __restrict__ agg, long long total)
{
    long long t = (long long)blockIdx.x * blockDim.x + threadIdx.x;
    if (t >= total) return;
    int e = (int)(t >> 5);
    int q = (int)(t & 31);
    int s = src[e], d = dst[e];
    float4 v = ld4(h + (size_t)s * H + q * 4);
    float4 sc = ld4(scale + q * 4);
    float4 sh = ld4(shift + q * 4);
    float a0 = fmaxf(v.x * sc.x + sh.x, 0.f);
    float a1 = fmaxf(v.y * sc.y + sh.y, 0.f);
    float a2 = fmaxf(v.z * sc.z + sh.z, 0.f);
    float a3 = fmaxf(v.w * sc.w + sh.w, 0.f);
    float* ap = agg + (size_t)d * H + q * 4;
    atomicAdd(ap + 0, a0); atomicAdd(ap + 1, a1);
    atomicAdd(ap + 2, a2); atomicAdd(ap + 3, a3);
}

// ---------------- GEMM1: out = leaky_relu(A @ W + b) ----------------
// 64 rows x 128 cols per 256-thread block; 8x4 accum per thread.
__global__ __launch_bounds__(256) void k_gemm_lin1(
    const float* __restrict__ A, const float* __restrict__ W, const float* __restrict__ bias,
    float* __restrict__ out, int n)
{
    __shared__ float sA[64][32];
    __shared__ float sW[32][128];
    const int tid = threadIdx.x;
    const int tx = tid & 31, ty = tid >> 5;
    const int rb = blockIdx.x * 64;
    float acc[8][4];
#pragma unroll
    for (int i = 0; i < 8; i++)
#pragma unroll
        for (int j = 0; j < 4; j++) acc[i][j] = 0.f;

    for (int k0 = 0; k0 < H; k0 += 32) {
#pragma unroll
        for (int j = 0; j < 2; j++) {
            int off = (tid * 2 + j) * 4;
            int r = off >> 5, kk = off & 31;
            int row = rb + r;
            float4 v = {0.f, 0.f, 0.f, 0.f};
            if (row < n) v = ld4(A + (size_t)row * H + k0 + kk);
            *reinterpret_cast<float4*>(&sA[r][kk]) = v;
        }
#pragma unroll
        for (int j = 0; j < 4; j++) {
            int off = (tid * 4 + j) * 4;
            int kk = off >> 7, c = off & 127;
            *reinterpret_cast<float4*>(&sW[kk][c]) = ld4(W + (size_t)(k0 + kk) * H + c);
        }
        __syncthreads();
#pragma unroll
        for (int kk = 0; kk < 32; ++kk) {
            float4 w = *reinterpret_cast<float4*>(&sW[kk][tx * 4]);
#pragma unroll
            for (int i = 0; i < 8; i++) {
                float a = sA[ty * 8 + i][kk];
                acc[i][0] += a * w.x; acc[i][1] += a * w.y;
                acc[i][2] += a * w.z; acc[i][3] += a * w.w;
            }
        }
        __syncthreads();
    }
    float4 b = ld4(bias + tx * 4);
#pragma unroll
    for (int i = 0; i < 8; i++) {
        int row = rb + ty * 8 + i;
        if (row < n) {
            float4 o;
            o.x = acc[i][0] + b.x; o.y = acc[i][1] + b.y;
            o.z = acc[i][2] + b.z; o.w = acc[i][3] + b.w;
            o.x = o.x > 0.f ? o.x : NEG_SLOPE * o.x;
            o.y = o.y > 0.f ? o.y : NEG_SLOPE * o.y;
            o.z = o.z > 0.f ? o.z : NEG_SLOPE * o.z;
            o.w = o.w > 0.f ? o.w : NEG_SLOPE * o.w;
            *reinterpret_cast<float4*>(out + (size_t)row * H + tx * 4) = o;
        }
    }
}

// ---- GEMM2: u = A @ W + b; row L2-normalize; write; accumulate BN column stats ----
__global__ __launch_bounds__(256) void k_gemm_lin2norm(
    const float* __restrict__ A, const float* __restrict__ W, const float* __restrict__ bias,
    float* __restrict__ out, float* __restrict__ gsum, float* __restrict__ gsumsq, int n)
{
    __shared__ float sA[64][32];
    __shared__ float sW[32][128];
    __shared__ float cs[128], css[128];
    const int tid = threadIdx.x;
    const int tx = tid & 31, ty = tid >> 5;
    const int rb = blockIdx.x * 64;
    if (tid < 128) { cs[tid] = 0.f; css[tid] = 0.f; }
    float acc[8][4];
#pragma unroll
    for (int i = 0; i < 8; i++)
#pragma unroll
        for (int j = 0; j < 4; j++) acc[i][j] = 0.f;

    for (int k0 = 0; k0 < H; k0 += 32) {
#pragma unroll
        for (int j = 0; j < 2; j++) {
            int off = (tid * 2 + j) * 4;
            int r = off >> 5, kk = off & 31;
            int row = rb + r;
            float4 v = {0.f, 0.f, 0.f, 0.f};
            if (row < n) v = ld4(A + (size_t)row * H + k0 + kk);
            *reinterpret_cast<float4*>(&sA[r][kk]) = v;
        }
#pragma unroll
        for (int j = 0; j < 4; j++) {
            int off = (tid * 4 + j) * 4;
            int kk = off >> 7, c = off & 127;
            *reinterpret_cast<float4*>(&sW[kk][c]) = ld4(W + (size_t)(k0 + kk) * H + c);
        }
        __syncthreads();
#pragma unroll
        for (int kk = 0; kk < 32; ++kk) {
            float4 w = *reinterpret_cast<float4*>(&sW[kk][tx * 4]);
#pragma unroll
            for (int i = 0; i < 8; i++) {
                float a = sA[ty * 8 + i][kk];
                acc[i][0] += a * w.x; acc[i][1] += a * w.y;
                acc[i][2] += a * w.z; acc[i][3] += a * w.w;
            }
        }
        __syncthreads();
    }
    float4 b = ld4(bias + tx * 4);
    float lsum[4] = {0.f, 0.f, 0.f, 0.f}, lss[4] = {0.f, 0.f, 0.f, 0.f};
#pragma unroll
    for (int i = 0; i < 8; i++) {
        int row = rb + ty * 8 + i;
        float u0 = acc[i][0] + b.x, u1 = acc[i][1] + b.y;
        float u2 = acc[i][2] + b.z, u3 = acc[i][3] + b.w;
        float ss = u0 * u0 + u1 * u1 + u2 * u2 + u3 * u3;
#pragma unroll
        for (int m = 1; m < 32; m <<= 1) ss += __shfl_xor(ss, m, 64);
        float inv = 1.0f / fmaxf(sqrtf(ss), 1e-12f);
        u0 *= inv; u1 *= inv; u2 *= inv; u3 *= inv;
        if (row < n) {
            float4 o = {u0, u1, u2, u3};
            *reinterpret_cast<float4*>(out + (size_t)row * H + tx * 4) = o;
            lsum[0] += u0; lsum[1] += u1; lsum[2] += u2; lsum[3] += u3;
            lss[0] += u0 * u0; lss[1] += u1 * u1; lss[2] += u2 * u2; lss[3] += u3 * u3;
        }
    }
#pragma unroll
    for (int j = 0; j < 4; j++) {
        atomicAdd(&cs[tx * 4 + j], lsum[j]);
        atomicAdd(&css[tx * 4 + j], lss[j]);
    }
    __syncthreads();
    if (tid < 128) {
        atomicAdd(gsum + tid, cs[tid]);
        atomicAdd(gsumsq + tid, css[tid]);
    }
}

// ---- SAGE: v = (agg/max(deg,1)) @ Wl + bl + relu(affine1(h)) @ Wr; BN2 stats ----
__global__ __launch_bounds__(256) void k_gemm_sage(
    const float* __restrict__ Aagg, const float* __restrict__ deg,
    const float* __restrict__ Hh, const float* __restrict__ scale1, const float* __restrict__ shift1,
    const float* __restrict__ Wl, const float* __restrict__ bl, const float* __restrict__ Wr,
    float* __restrict__ out, float* __restrict__ gsum, float* __restrict__ gsumsq, int n)
{
    __shared__ float sA1[64][32];
    __shared__ float sA2[64][32];
    __shared__ float sW1[32][128];
    __shared__ float sW2[32][128];
    __shared__ float cs[128], css[128];
    const int tid = threadIdx.x;
    const int tx = tid & 31, ty = tid >> 5;
    const int rb = blockIdx.x * 64;
    if (tid < 128) { cs[tid] = 0.f; css[tid] = 0.f; }
    float acc[8][4];
#pragma unroll
    for (int i = 0; i < 8; i++)
#pragma unroll
        for (int j = 0; j < 4; j++) acc[i][j] = 0.f;

    for (int k0 = 0; k0 < H; k0 += 32) {
#pragma unroll
        for (int j = 0; j < 2; j++) {
            int off = (tid * 2 + j) * 4;
            int r = off >> 5, kk = off & 31;
            int row = rb + r;
            float4 v1 = {0.f, 0.f, 0.f, 0.f};
            float4 v2 = {0.f, 0.f, 0.f, 0.f};
            if (row < n) {
                v1 = ld4(Aagg + (size_t)row * H + k0 + kk);
                float idv = 1.0f / fmaxf(deg[row], 1.0f);
                v1.x *= idv; v1.y *= idv; v1.z *= idv; v1.w *= idv;
                float4 hv = ld4(Hh + (size_t)row * H + k0 + kk);
                float4 sc = ld4(scale1 + k0 + kk);
                float4 sh = ld4(shift1 + k0 + kk);
                v2.x = fmaxf(hv.x * sc.x + sh.x, 0.f);
                v2.y = fmaxf(hv.y * sc.y + sh.y, 0.f);
                v2.z = fmaxf(hv.z * sc.z + sh.z, 0.f);
                v2.w = fmaxf(hv.w * sc.w + sh.w, 0.f);
            }
            *reinterpret_cast<float4*>(&sA1[r][kk]) = v1;
            *reinterpret_cast<float4*>(&sA2[r][kk]) = v2;
        }
#pragma unroll
        for (int j = 0; j < 4; j++) {
            int off = (tid * 4 + j) * 4;
            int kk = off >> 7, c = off & 127;
            *reinterpret_cast<float4*>(&sW1[kk][c]) = ld4(Wl + (size_t)(k0 + kk) * H + c);
            *reinterpret_cast<float4*>(&sW2[kk][c]) = ld4(Wr + (size_t)(k0 + kk) * H + c);
        }
        __syncthreads();
#pragma unroll
        for (int kk = 0; kk < 32; ++kk) {
            float4 w1 = *reinterpret_cast<float4*>(&sW1[kk][tx * 4]);
            float4 w2 = *reinterpret_cast<float4*>(&sW2[kk][tx * 4]);
#pragma unroll
            for (int i = 0; i < 8; i++) {
                float a1 = sA1[ty * 8 + i][kk];
                float a2 = sA2[ty * 8 + i][kk];
                acc[i][0] += a1 * w1.x + a2 * w2.x;
                acc[i][1] += a1 * w1.y + a2 * w2.y;
                acc[i][2] += a1 * w1.z + a2 * w2.z;
                acc[i][3] += a1 * w1.w + a2 * w2.w;
            }
        }
        __syncthreads();
    }
    float4 b = ld4(bl + tx * 4);
    float lsum[4] = {0.f, 0.f, 0.f, 0.f}, lss[4] = {0.f, 0.f, 0.f, 0.f};
#pragma unroll
    for (int i = 0; i < 8; i++) {
        int row = rb + ty * 8 + i;
        if (row < n) {
            float u0 = acc[i][0] + b.x, u1 = acc[i][1] + b.y;
            float u2 = acc[i][2] + b.z, u3 = acc[i][3] + b.w;
            float4 o = {u0, u1, u2, u3};
            *reinterpret_cast<float4*>(out + (size_t)row * H + tx * 4) = o;
            lsum[0] += u0; lsum[1] += u1; lsum[2] += u2; lsum[3] += u3;
            lss[0] += u0 * u0; lss[1] += u1 * u1; lss[2] += u2 * u2; lss[3] += u3 * u3;
        }
    }
#pragma unroll
    for (int j = 0; j < 4; j++) {
        atomicAdd(&cs[tx * 4 + j], lsum[j]);
        atomicAdd(&css[tx * 4 + j], lss[j]);
    }
    __syncthreads();
    if (tid < 128) {
        atomicAdd(gsum + tid, cs[tid]);
        atomicAdd(gsumsq + tid, css[tid]);
    }
}

// ---------------- BN params: scale/shift from sums ----------------
__global__ void k_bnparams(const float* __restrict__ gsum, const float* __restrict__ gsumsq,
                           const float* __restrict__ g, const float* __restrict__ b,
                           float* __restrict__ scale, float* __restrict__ shift, float inv_n)
{
    int c = threadIdx.x;
    float mu = gsum[c] * inv_n;
    float var = fmaxf(gsumsq[c] * inv_n - mu * mu, 0.f);
    float sc = g[c] * rsqrtf(var + BN_EPS);
    scale[c] = sc;
    shift[c] = b[c] - mu * sc;
}

__global__ void k_dinv(const float* __restrict__ deg, float* __restrict__ dinv, int n)
{
    int i = blockIdx.x * blockDim.x + threadIdx.x;
    if (i < n) dinv[i] = rsqrtf(deg[i] + 1.0f);
}

// ---- GCN: xw = relu(affine2(h2)) @ Wg ; out = dinv^2 * xw (self-loop term) ----
__global__ __launch_bounds__(320) void k_gcn(
    const float* __restrict__ H2, const float* __restrict__ scale2, const float* __restrict__ shift2,
    const float* __restrict__ Wg, const float* __restrict__ dinv,
    float* __restrict__ xw, float* __restrict__ outp, int n)
{
    __shared__ float sW[H * OUTD];   // 128*40 = 20KB
    __shared__ float sA[32][H];      // 16KB
    const int tid = threadIdx.x;
#pragma unroll
    for (int j = 0; j < 4; j++) {
        int off = (tid + j * 320) * 4;
        *reinterpret_cast<float4*>(&sW[off]) = ld4(Wg + off);
    }
    const int rb = blockIdx.x * 32;
#pragma unroll
    for (int j = 0; j < 4; j++) {
        int li = tid + j * 320;
        if (li < 1024) {
            int off = li * 4;
            int r = off >> 7, kk = off & 127;
            int row = rb + r;
            float4 v = {0.f, 0.f, 0.f, 0.f};
            if (row < n) {
                float4 hv = ld4(H2 + (size_t)row * H + kk);
                float4 sc = ld4(scale2 + kk);
                float4 sh = ld4(shift2 + kk);
                v.x = fmaxf(hv.x * sc.x + sh.x, 0.f);
                v.y = fmaxf(hv.y * sc.y + sh.y, 0.f);
                v.z = fmaxf(hv.z * sc.z + sh.z, 0.f);
                v.w = fmaxf(hv.w * sc.w + sh.w, 0.f);
            }
            *reinterpret_cast<float4*>(&sA[r][kk]) = v;
        }
    }
    __syncthreads();
    const int c = tid % OUTD;
    const int rg = tid / OUTD;      // 0..7
    float acc[4] = {0.f, 0.f, 0.f, 0.f};
    for (int k = 0; k < H; k++) {
        float w = sW[k * OUTD + c];
#pragma unroll
        for (int i = 0; i < 4; i++) acc[i] += sA[rg + i * 8][k] * w;
    }
#pragma unroll
    for (int i = 0; i < 4; i++) {
        int row = rb + rg + i * 8;
        if (row < n) {
            float di = dinv[row];
            xw[(size_t)row * OUTD + c] = acc[i];
            outp[(size_t)row * OUTD + c] = di * di * acc[i];
        }
    }
}

// ---- scatter3: out[dst] += dinv[src]*dinv[dst]*xw[src] ----
__global__ __launch_bounds__(256) void k_scatter3(
    const float* __restrict__ xw, const float* __restrict__ dinv,
    const int* __restrict__ src, const int* __restrict__ dst,
    float* __restrict__ outp, long long total)
{
    long long t = (long long)blockIdx.x * blockDim.x + threadIdx.x;
    if (t >= total) return;
    int e = (int)(t >> 6);
    int c = (int)(t & 63);
    if (c >= OUTD) return;
    int s = src[e], d = dst[e];
    float nrm = dinv[s] * dinv[d];
    atomicAdd(outp + (size_t)d * OUTD + c, nrm * xw[(size_t)s * OUTD + c]);
}

// ---- log_softmax (+ gcn bias), one wave per row ----
__global__ __launch_bounds__(256) void k_logsoftmax(
    float* __restrict__ outp, const float* __restrict__ bias, int n)
{
    int wid = (int)(((long long)blockIdx.x * blockDim.x + threadIdx.x) >> 6);
    int lane = threadIdx.x & 63;
    if (wid >= n) return;
    float vb = 0.f;
    float v = -INFINITY;
    if (lane < OUTD) {
        vb = outp[(size_t)wid * OUTD + lane] + bias[lane];
        v = vb;
    }
    float m = v;
#pragma unroll
    for (int s = 1; s < 64; s <<= 1) m = fmaxf(m, __shfl_xor(m, s, 64));
    float ex = (lane < OUTD) ? expf(vb - m) : 0.f;
    float sum = ex;
#pragma unroll
    for (int s = 1; s < 64; s <<= 1) sum += __shfl_xor(sum, s, 64);
    float l = logf(sum);
    if (lane < OUTD) outp[(size_t)wid * OUTD + lane] = vb - m - l;
}

extern "C" void kernel_launch(void* const* d_in, const int* in_sizes, int n_in,
                              void* d_out, int out_size, void* d_ws, size_t ws_size,
                              hipStream_t stream)
{
    const float* x     = (const float*)d_in[0];
    const int*   ei    = (const int*)d_in[1];
    const float* w1    = (const float*)d_in[2];
    const float* b1    = (const float*)d_in[3];
    const float* w2    = (const float*)d_in[4];
    const float* b2    = (const float*)d_in[5];
    const float* bn1g  = (const float*)d_in[6];
    const float* bn1b  = (const float*)d_in[7];
    const float* wl    = (const float*)d_in[8];
    const float* bls   = (const float*)d_in[9];
    const float* wr    = (const float*)d_in[10];
    const float* bn2g  = (const float*)d_in[11];
    const float* bn2b  = (const float*)d_in[12];
    const float* wg    = (const float*)d_in[13];
    const float* bg    = (const float*)d_in[14];

    const int N = in_sizes[0] / H;
    const int E = in_sizes[1] / 2;
    const int* src = ei;
    const int* dst = ei + E;
    float* outp = (float*)d_out;

    float* B0   = (float*)d_ws;                 // N*H
    float* B1   = B0 + (size_t)N * H;           // N*H
    float* deg  = B1 + (size_t)N * H;           // N
    float* dinv = deg + N;                      // N
    float* st   = dinv + N;                     // 1024 floats
    float* sum1 = st,        *sumsq1 = st + 128;
    float* sum2 = st + 256,  *sumsq2 = st + 384;
    float* scale1 = st + 512, *shift1 = st + 640;
    float* scale2 = st + 768, *shift2 = st + 896;

    // zero the accumulation buffers (ws is poisoned, and replays must be deterministic)
    hipMemsetAsync(B0, 0, (size_t)N * H * sizeof(float), stream);
    hipMemsetAsync(deg, 0, (size_t)N * sizeof(float), stream);
    hipMemsetAsync(st, 0, 1024 * sizeof(float), stream);

    const long long tot1 = (long long)E * 32;
    const int sblk = (int)((tot1 + 255) / 256);
    k_scatter1<<<sblk, 256, 0, stream>>>(x, src, dst, B0, deg, tot1);

    const int gblocks = (N + 63) / 64;
    k_gemm_lin1<<<gblocks, 256, 0, stream>>>(B0, w1, b1, B1, N);
    k_gemm_lin2norm<<<gblocks, 256, 0, stream>>>(B1, w2, b2, B0, sum1, sumsq1, N);
    k_bnparams<<<1, 128, 0, stream>>>(sum1, sumsq1, bn1g, bn1b, scale1, shift1, 1.0f / N);

    hipMemsetAsync(B1, 0, (size_t)N * H * sizeof(float), stream);
    k_scatter2<<<sblk, 256, 0, stream>>>(B0, scale1, shift1, src, dst, B1, tot1);
    // writes h2 back into B1 (row-local: each block reads/writes only its own rows)
    k_gemm_sage<<<gblocks, 256, 0, stream>>>(B1, deg, B0, scale1, shift1,
                                             wl, bls, wr, B1, sum2, sumsq2, N);
    k_bnparams<<<1, 128, 0, stream>>>(sum2, sumsq2, bn2g, bn2b, scale2, shift2, 1.0f / N);
    k_dinv<<<(N + 255) / 256, 256, 0, stream>>>(deg, dinv, N);

    const int gcnblocks = (N + 31) / 32;
    k_gcn<<<gcnblocks, 320, 0, stream>>>(B1, scale2, shift2, wg, dinv, B0, outp, N);

    const long long tot3 = (long long)E * 64;
    k_scatter3<<<(int)((tot3 + 255) / 256), 256, 0, stream>>>(B0, dinv, src, dst, outp, tot3);

    k_logsoftmax<<<((long long)N * 64 + 255) / 256, 256, 0, stream>>>(outp, bg, N);
}

// Round 2
// 879.655 us; speedup vs baseline: 6.9970x; 6.9970x over previous
//
#include <hip/hip_runtime.h>
#include <math.h>

#define H 128
#define OUTD 40
#define BN_EPS 1e-5f
#define NEG_SLOPE 0.01f

__device__ __forceinline__ float4 ld4(const float* p) {
    return *reinterpret_cast<const float4*>(p);
}
__device__ __forceinline__ float2 ld2(const float* p) {
    return *reinterpret_cast<const float2*>(p);
}

// ================= CSR build =================
__global__ __launch_bounds__(256) void k_hist(
    const int* __restrict__ dst, int* __restrict__ deg, int E)
{
    int e = blockIdx.x * 256 + threadIdx.x;
    if (e < E) atomicAdd(&deg[dst[e]], 1);
}

// block-local exclusive scan (1024 elems/block), block totals to bsum
__global__ __launch_bounds__(256) void k_scan1(
    const int* __restrict__ deg, int* __restrict__ cursor, int* __restrict__ bsum, int n)
{
    __shared__ int sums[256];
    const int tid = threadIdx.x;
    const int idx = blockIdx.x * 1024 + tid * 4;
    int4 v = {0, 0, 0, 0};
    if (idx + 3 < n) v = *reinterpret_cast<const int4*>(deg + idx);
    else {
        if (idx + 0 < n) v.x = deg[idx + 0];
        if (idx + 1 < n) v.y = deg[idx + 1];
        if (idx + 2 < n) v.z = deg[idx + 2];
        if (idx + 3 < n) v.w = deg[idx + 3];
    }
    int t = v.x + v.y + v.z + v.w;
    sums[tid] = t;
    __syncthreads();
    for (int off = 1; off < 256; off <<= 1) {
        int other = (tid >= off) ? sums[tid - off] : 0;
        __syncthreads();
        sums[tid] += other;
        __syncthreads();
    }
    int incl = sums[tid];
    int excl = incl - t;
    if (tid == 255) bsum[blockIdx.x] = incl;
    int c0 = excl, c1 = c0 + v.x, c2 = c1 + v.y, c3 = c2 + v.z;
    if (idx + 3 < n) {
        int4 o = {c0, c1, c2, c3};
        *reinterpret_cast<int4*>(cursor + idx) = o;
    } else {
        if (idx + 0 < n) cursor[idx + 0] = c0;
        if (idx + 1 < n) cursor[idx + 1] = c1;
        if (idx + 2 < n) cursor[idx + 2] = c2;
        if (idx + 3 < n) cursor[idx + 3] = c3;
    }
}

__global__ void k_scan2(int* __restrict__ bsum, int nb)
{
    __shared__ int s[1024];
    const int tid = threadIdx.x;
    for (int i = tid; i < nb; i += blockDim.x) s[i] = bsum[i];
    __syncthreads();
    if (tid == 0) {
        int acc = 0;
        for (int i = 0; i < nb; i++) { int t = s[i]; s[i] = acc; acc += t; }
    }
    __syncthreads();
    for (int i = tid; i < nb; i += blockDim.x) bsum[i] = s[i];
}

__global__ __launch_bounds__(256) void k_scan3(
    int* __restrict__ cursor, const int* __restrict__ bsum, int n)
{
    int i = blockIdx.x * 256 + threadIdx.x;
    if (i < n) cursor[i] += bsum[i >> 10];
}

// fill: cursor starts as row-start offsets; ends as row-end offsets
__global__ __launch_bounds__(256) void k_fill(
    const int* __restrict__ src, const int* __restrict__ dst,
    int* __restrict__ cursor, int* __restrict__ csr, int E)
{
    int e = blockIdx.x * 256 + threadIdx.x;
    if (e >= E) return;
    int d = dst[e];
    int pos = atomicAdd(&cursor[d], 1);
    csr[pos] = src[e];
}

__global__ __launch_bounds__(256) void k_dinv(
    const int* __restrict__ deg, float* __restrict__ dinv, int n)
{
    int i = blockIdx.x * 256 + threadIdx.x;
    if (i < n) dinv[i] = rsqrtf((float)deg[i] + 1.0f);
}

// ================= gather aggregations =================
// one wave per row; lane handles 2 columns of 128
__global__ __launch_bounds__(256) void k_agg1(
    const float* __restrict__ x, const int* __restrict__ csr,
    const int* __restrict__ cursor, const int* __restrict__ deg,
    float* __restrict__ out, int n)
{
    int wid = (blockIdx.x * 256 + threadIdx.x) >> 6;
    int lane = threadIdx.x & 63;
    if (wid >= n) return;
    int end = cursor[wid];
    int start = end - deg[wid];
    float2 acc = {0.f, 0.f};
    int i = start;
    for (; i + 4 <= end; i += 4) {
        int s0 = csr[i], s1 = csr[i + 1], s2 = csr[i + 2], s3 = csr[i + 3];
        float2 v0 = ld2(x + (size_t)s0 * H + lane * 2);
        float2 v1 = ld2(x + (size_t)s1 * H + lane * 2);
        float2 v2 = ld2(x + (size_t)s2 * H + lane * 2);
        float2 v3 = ld2(x + (size_t)s3 * H + lane * 2);
        acc.x += (v0.x + v1.x) + (v2.x + v3.x);
        acc.y += (v0.y + v1.y) + (v2.y + v3.y);
    }
    for (; i < end; i++) {
        int s = csr[i];
        float2 v = ld2(x + (size_t)s * H + lane * 2);
        acc.x += v.x; acc.y += v.y;
    }
    *reinterpret_cast<float2*>(out + (size_t)wid * H + lane * 2) = acc;
}

// mean of relu(affine1(h[src])) over neighbors
__global__ __launch_bounds__(256) void k_agg2(
    const float* __restrict__ h, const float* __restrict__ scale, const float* __restrict__ shift,
    const int* __restrict__ csr, const int* __restrict__ cursor, const int* __restrict__ deg,
    float* __restrict__ out, int n)
{
    int wid = (blockIdx.x * 256 + threadIdx.x) >> 6;
    int lane = threadIdx.x & 63;
    if (wid >= n) return;
    int end = cursor[wid];
    int dg = deg[wid];
    int start = end - dg;
    float2 sc = ld2(scale + lane * 2);
    float2 sh = ld2(shift + lane * 2);
    float2 acc = {0.f, 0.f};
    int i = start;
    for (; i + 4 <= end; i += 4) {
        int s0 = csr[i], s1 = csr[i + 1], s2 = csr[i + 2], s3 = csr[i + 3];
        float2 v0 = ld2(h + (size_t)s0 * H + lane * 2);
        float2 v1 = ld2(h + (size_t)s1 * H + lane * 2);
        float2 v2 = ld2(h + (size_t)s2 * H + lane * 2);
        float2 v3 = ld2(h + (size_t)s3 * H + lane * 2);
        acc.x += fmaxf(v0.x * sc.x + sh.x, 0.f) + fmaxf(v1.x * sc.x + sh.x, 0.f)
               + fmaxf(v2.x * sc.x + sh.x, 0.f) + fmaxf(v3.x * sc.x + sh.x, 0.f);
        acc.y += fmaxf(v0.y * sc.y + sh.y, 0.f) + fmaxf(v1.y * sc.y + sh.y, 0.f)
               + fmaxf(v2.y * sc.y + sh.y, 0.f) + fmaxf(v3.y * sc.y + sh.y, 0.f);
    }
    for (; i < end; i++) {
        int s = csr[i];
        float2 v = ld2(h + (size_t)s * H + lane * 2);
        acc.x += fmaxf(v.x * sc.x + sh.x, 0.f);
        acc.y += fmaxf(v.y * sc.y + sh.y, 0.f);
    }
    float idv = 1.0f / fmaxf((float)dg, 1.0f);
    acc.x *= idv; acc.y *= idv;
    *reinterpret_cast<float2*>(out + (size_t)wid * H + lane * 2) = acc;
}

// GCN gather + self-loop + bias + log-softmax, one wave per row (lanes 0..39 active)
// xws[r] = dinv[r] * (act2(h2[r]) @ Wg)   (pre-scaled in k_gcn)
__global__ __launch_bounds__(256) void k_agg3(
    const float* __restrict__ xws, const float* __restrict__ dinv,
    const int* __restrict__ csr, const int* __restrict__ cursor, const int* __restrict__ deg,
    const float* __restrict__ bias, float* __restrict__ outp, int n)
{
    int wid = (blockIdx.x * 256 + threadIdx.x) >> 6;
    int lane = threadIdx.x & 63;
    if (wid >= n) return;
    int end = cursor[wid];
    int start = end - deg[wid];
    bool act = lane < OUTD;
    int col = act ? lane : 0;
    float acc = 0.f;
    int i = start;
    for (; i + 4 <= end; i += 4) {
        int s0 = csr[i], s1 = csr[i + 1], s2 = csr[i + 2], s3 = csr[i + 3];
        float a0 = xws[(size_t)s0 * OUTD + col];
        float a1 = xws[(size_t)s1 * OUTD + col];
        float a2 = xws[(size_t)s2 * OUTD + col];
        float a3 = xws[(size_t)s3 * OUTD + col];
        acc += (a0 + a1) + (a2 + a3);
    }
    for (; i < end; i++) {
        int s = csr[i];
        acc += xws[(size_t)s * OUTD + col];
    }
    float di = dinv[wid];
    float v = di * (acc + xws[(size_t)wid * OUTD + col]) + bias[col];
    float m = act ? v : -INFINITY;
#pragma unroll
    for (int s = 1; s < 64; s <<= 1) m = fmaxf(m, __shfl_xor(m, s, 64));
    float ex = act ? expf(v - m) : 0.f;
    float sum = ex;
#pragma unroll
    for (int s = 1; s < 64; s <<= 1) sum += __shfl_xor(sum, s, 64);
    float l = logf(sum);
    if (act) outp[(size_t)wid * OUTD + lane] = v - m - l;
}

// ================= dense layers =================
// GEMM1: out = leaky_relu(A @ W + b); 64x128 per block
__global__ __launch_bounds__(256) void k_gemm_lin1(
    const float* __restrict__ A, const float* __restrict__ W, const float* __restrict__ bias,
    float* __restrict__ out, int n)
{
    __shared__ float sA[64][32];
    __shared__ float sW[32][128];
    const int tid = threadIdx.x;
    const int tx = tid & 31, ty = tid >> 5;
    const int rb = blockIdx.x * 64;
    float acc[8][4];
#pragma unroll
    for (int i = 0; i < 8; i++)
#pragma unroll
        for (int j = 0; j < 4; j++) acc[i][j] = 0.f;

    for (int k0 = 0; k0 < H; k0 += 32) {
#pragma unroll
        for (int j = 0; j < 2; j++) {
            int off = (tid * 2 + j) * 4;
            int r = off >> 5, kk = off & 31;
            int row = rb + r;
            float4 v = {0.f, 0.f, 0.f, 0.f};
            if (row < n) v = ld4(A + (size_t)row * H + k0 + kk);
            *reinterpret_cast<float4*>(&sA[r][kk]) = v;
        }
#pragma unroll
        for (int j = 0; j < 4; j++) {
            int off = (tid * 4 + j) * 4;
            int kk = off >> 7, c = off & 127;
            *reinterpret_cast<float4*>(&sW[kk][c]) = ld4(W + (size_t)(k0 + kk) * H + c);
        }
        __syncthreads();
#pragma unroll
        for (int kk = 0; kk < 32; ++kk) {
            float4 w = *reinterpret_cast<float4*>(&sW[kk][tx * 4]);
#pragma unroll
            for (int i = 0; i < 8; i++) {
                float a = sA[ty * 8 + i][kk];
                acc[i][0] += a * w.x; acc[i][1] += a * w.y;
                acc[i][2] += a * w.z; acc[i][3] += a * w.w;
            }
        }
        __syncthreads();
    }
    float4 b = ld4(bias + tx * 4);
#pragma unroll
    for (int i = 0; i < 8; i++) {
        int row = rb + ty * 8 + i;
        if (row < n) {
            float4 o;
            o.x = acc[i][0] + b.x; o.y = acc[i][1] + b.y;
            o.z = acc[i][2] + b.z; o.w = acc[i][3] + b.w;
            o.x = o.x > 0.f ? o.x : NEG_SLOPE * o.x;
            o.y = o.y > 0.f ? o.y : NEG_SLOPE * o.y;
            o.z = o.z > 0.f ? o.z : NEG_SLOPE * o.z;
            o.w = o.w > 0.f ? o.w : NEG_SLOPE * o.w;
            *reinterpret_cast<float4*>(out + (size_t)row * H + tx * 4) = o;
        }
    }
}

// GEMM2: u = A @ W + b; row L2-normalize; write; accumulate BN column stats
__global__ __launch_bounds__(256) void k_gemm_lin2norm(
    const float* __restrict__ A, const float* __restrict__ W, const float* __restrict__ bias,
    float* __restrict__ out, float* __restrict__ gsum, float* __restrict__ gsumsq, int n)
{
    __shared__ float sA[64][32];
    __shared__ float sW[32][128];
    __shared__ float cs[128], css[128];
    const int tid = threadIdx.x;
    const int tx = tid & 31, ty = tid >> 5;
    const int rb = blockIdx.x * 64;
    if (tid < 128) { cs[tid] = 0.f; css[tid] = 0.f; }
    float acc[8][4];
#pragma unroll
    for (int i = 0; i < 8; i++)
#pragma unroll
        for (int j = 0; j < 4; j++) acc[i][j] = 0.f;

    for (int k0 = 0; k0 < H; k0 += 32) {
#pragma unroll
        for (int j = 0; j < 2; j++) {
            int off = (tid * 2 + j) * 4;
            int r = off >> 5, kk = off & 31;
            int row = rb + r;
            float4 v = {0.f, 0.f, 0.f, 0.f};
            if (row < n) v = ld4(A + (size_t)row * H + k0 + kk);
            *reinterpret_cast<float4*>(&sA[r][kk]) = v;
        }
#pragma unroll
        for (int j = 0; j < 4; j++) {
            int off = (tid * 4 + j) * 4;
            int kk = off >> 7, c = off & 127;
            *reinterpret_cast<float4*>(&sW[kk][c]) = ld4(W + (size_t)(k0 + kk) * H + c);
        }
        __syncthreads();
#pragma unroll
        for (int kk = 0; kk < 32; ++kk) {
            float4 w = *reinterpret_cast<float4*>(&sW[kk][tx * 4]);
#pragma unroll
            for (int i = 0; i < 8; i++) {
                float a = sA[ty * 8 + i][kk];
                acc[i][0] += a * w.x; acc[i][1] += a * w.y;
                acc[i][2] += a * w.z; acc[i][3] += a * w.w;
            }
        }
        __syncthreads();
    }
    float4 b = ld4(bias + tx * 4);
    float lsum[4] = {0.f, 0.f, 0.f, 0.f}, lss[4] = {0.f, 0.f, 0.f, 0.f};
#pragma unroll
    for (int i = 0; i < 8; i++) {
        int row = rb + ty * 8 + i;
        float u0 = acc[i][0] + b.x, u1 = acc[i][1] + b.y;
        float u2 = acc[i][2] + b.z, u3 = acc[i][3] + b.w;
        float ss = u0 * u0 + u1 * u1 + u2 * u2 + u3 * u3;
#pragma unroll
        for (int m = 1; m < 32; m <<= 1) ss += __shfl_xor(ss, m, 64);
        float inv = 1.0f / fmaxf(sqrtf(ss), 1e-12f);
        u0 *= inv; u1 *= inv; u2 *= inv; u3 *= inv;
        if (row < n) {
            float4 o = {u0, u1, u2, u3};
            *reinterpret_cast<float4*>(out + (size_t)row * H + tx * 4) = o;
            lsum[0] += u0; lsum[1] += u1; lsum[2] += u2; lsum[3] += u3;
            lss[0] += u0 * u0; lss[1] += u1 * u1; lss[2] += u2 * u2; lss[3] += u3 * u3;
        }
    }
#pragma unroll
    for (int j = 0; j < 4; j++) {
        atomicAdd(&cs[tx * 4 + j], lsum[j]);
        atomicAdd(&css[tx * 4 + j], lss[j]);
    }
    __syncthreads();
    if (tid < 128) {
        atomicAdd(gsum + tid, cs[tid]);
        atomicAdd(gsumsq + tid, css[tid]);
    }
}

// SAGE: v = meanagg @ Wl + bl + relu(affine1(h)) @ Wr; BN2 stats
__global__ __launch_bounds__(256) void k_gemm_sage(
    const float* __restrict__ Aagg,
    const float* __restrict__ Hh, const float* __restrict__ scale1, const float* __restrict__ shift1,
    const float* __restrict__ Wl, const float* __restrict__ bl, const float* __restrict__ Wr,
    float* __restrict__ out, float* __restrict__ gsum, float* __restrict__ gsumsq, int n)
{
    __shared__ float sA1[64][32];
    __shared__ float sA2[64][32];
    __shared__ float sW1[32][128];
    __shared__ float sW2[32][128];
    __shared__ float cs[128], css[128];
    const int tid = threadIdx.x;
    const int tx = tid & 31, ty = tid >> 5;
    const int rb = blockIdx.x * 64;
    if (tid < 128) { cs[tid] = 0.f; css[tid] = 0.f; }
    float acc[8][4];
#pragma unroll
    for (int i = 0; i < 8; i++)
#pragma unroll
        for (int j = 0; j < 4; j++) acc[i][j] = 0.f;

    for (int k0 = 0; k0 < H; k0 += 32) {
#pragma unroll
        for (int j = 0; j < 2; j++) {
            int off = (tid * 2 + j) * 4;
            int r = off >> 5, kk = off & 31;
            int row = rb + r;
            float4 v1 = {0.f, 0.f, 0.f, 0.f};
            float4 v2 = {0.f, 0.f, 0.f, 0.f};
            if (row < n) {
                v1 = ld4(Aagg + (size_t)row * H + k0 + kk);
                float4 hv = ld4(Hh + (size_t)row * H + k0 + kk);
                float4 sc = ld4(scale1 + k0 + kk);
                float4 sh = ld4(shift1 + k0 + kk);
                v2.x = fmaxf(hv.x * sc.x + sh.x, 0.f);
                v2.y = fmaxf(hv.y * sc.y + sh.y, 0.f);
                v2.z = fmaxf(hv.z * sc.z + sh.z, 0.f);
                v2.w = fmaxf(hv.w * sc.w + sh.w, 0.f);
            }
            *reinterpret_cast<float4*>(&sA1[r][kk]) = v1;
            *reinterpret_cast<float4*>(&sA2[r][kk]) = v2;
        }
#pragma unroll
        for (int j = 0; j < 4; j++) {
            int off = (tid * 4 + j) * 4;
            int kk = off >> 7, c = off & 127;
            *reinterpret_cast<float4*>(&sW1[kk][c]) = ld4(Wl + (size_t)(k0 + kk) * H + c);
            *reinterpret_cast<float4*>(&sW2[kk][c]) = ld4(Wr + (size_t)(k0 + kk) * H + c);
        }
        __syncthreads();
#pragma unroll
        for (int kk = 0; kk < 32; ++kk) {
            float4 w1 = *reinterpret_cast<float4*>(&sW1[kk][tx * 4]);
            float4 w2 = *reinterpret_cast<float4*>(&sW2[kk][tx * 4]);
#pragma unroll
            for (int i = 0; i < 8; i++) {
                float a1 = sA1[ty * 8 + i][kk];
                float a2 = sA2[ty * 8 + i][kk];
                acc[i][0] += a1 * w1.x + a2 * w2.x;
                acc[i][1] += a1 * w1.y + a2 * w2.y;
                acc[i][2] += a1 * w1.z + a2 * w2.z;
                acc[i][3] += a1 * w1.w + a2 * w2.w;
            }
        }
        __syncthreads();
    }
    float4 b = ld4(bl + tx * 4);
    float lsum[4] = {0.f, 0.f, 0.f, 0.f}, lss[4] = {0.f, 0.f, 0.f, 0.f};
#pragma unroll
    for (int i = 0; i < 8; i++) {
        int row = rb + ty * 8 + i;
        if (row < n) {
            float u0 = acc[i][0] + b.x, u1 = acc[i][1] + b.y;
            float u2 = acc[i][2] + b.z, u3 = acc[i][3] + b.w;
            float4 o = {u0, u1, u2, u3};
            *reinterpret_cast<float4*>(out + (size_t)row * H + tx * 4) = o;
            lsum[0] += u0; lsum[1] += u1; lsum[2] += u2; lsum[3] += u3;
            lss[0] += u0 * u0; lss[1] += u1 * u1; lss[2] += u2 * u2; lss[3] += u3 * u3;
        }
    }
#pragma unroll
    for (int j = 0; j < 4; j++) {
        atomicAdd(&cs[tx * 4 + j], lsum[j]);
        atomicAdd(&css[tx * 4 + j], lss[j]);
    }
    __syncthreads();
    if (tid < 128) {
        atomicAdd(gsum + tid, cs[tid]);
        atomicAdd(gsumsq + tid, css[tid]);
    }
}

__global__ void k_bnparams(const float* __restrict__ gsum, const float* __restrict__ gsumsq,
                           const float* __restrict__ g, const float* __restrict__ b,
                           float* __restrict__ scale, float* __restrict__ shift, float inv_n)
{
    int c = threadIdx.x;
    float mu = gsum[c] * inv_n;
    float var = fmaxf(gsumsq[c] * inv_n - mu * mu, 0.f);
    float sc = g[c] * rsqrtf(var + BN_EPS);
    scale[c] = sc;
    shift[c] = b[c] - mu * sc;
}

// GCN dense part: xws = dinv[row] * (relu(affine2(h2)) @ Wg)
__global__ __launch_bounds__(320) void k_gcn(
    const float* __restrict__ H2, const float* __restrict__ scale2, const float* __restrict__ shift2,
    const float* __restrict__ Wg, const float* __restrict__ dinv,
    float* __restrict__ xws, int n)
{
    __shared__ float sW[H * OUTD];   // 20KB
    __shared__ float sA[32][H];      // 16KB
    const int tid = threadIdx.x;
#pragma unroll
    for (int j = 0; j < 4; j++) {
        int off = (tid + j * 320) * 4;
        *reinterpret_cast<float4*>(&sW[off]) = ld4(Wg + off);
    }
    const int rb = blockIdx.x * 32;
#pragma unroll
    for (int j = 0; j < 4; j++) {
        int li = tid + j * 320;
        if (li < 1024) {
            int off = li * 4;
            int r = off >> 7, kk = off & 127;
            int row = rb + r;
            float4 v = {0.f, 0.f, 0.f, 0.f};
            if (row < n) {
                float4 hv = ld4(H2 + (size_t)row * H + kk);
                float4 sc = ld4(scale2 + kk);
                float4 sh = ld4(shift2 + kk);
                v.x = fmaxf(hv.x * sc.x + sh.x, 0.f);
                v.y = fmaxf(hv.y * sc.y + sh.y, 0.f);
                v.z = fmaxf(hv.z * sc.z + sh.z, 0.f);
                v.w = fmaxf(hv.w * sc.w + sh.w, 0.f);
            }
            *reinterpret_cast<float4*>(&sA[r][kk]) = v;
        }
    }
    __syncthreads();
    const int c = tid % OUTD;
    const int rg = tid / OUTD;      // 0..7
    float acc[4] = {0.f, 0.f, 0.f, 0.f};
    for (int k = 0; k < H; k++) {
        float w = sW[k * OUTD + c];
#pragma unroll
        for (int i = 0; i < 4; i++) acc[i] += sA[rg + i * 8][k] * w;
    }
#pragma unroll
    for (int i = 0; i < 4; i++) {
        int row = rb + rg + i * 8;
        if (row < n) xws[(size_t)row * OUTD + c] = dinv[row] * acc[i];
    }
}

extern "C" void kernel_launch(void* const* d_in, const int* in_sizes, int n_in,
                              void* d_out, int out_size, void* d_ws, size_t ws_size,
                              hipStream_t stream)
{
    const float* x     = (const float*)d_in[0];
    const int*   ei    = (const int*)d_in[1];
    const float* w1    = (const float*)d_in[2];
    const float* b1    = (const float*)d_in[3];
    const float* w2    = (const float*)d_in[4];
    const float* b2    = (const float*)d_in[5];
    const float* bn1g  = (const float*)d_in[6];
    const float* bn1b  = (const float*)d_in[7];
    const float* wl    = (const float*)d_in[8];
    const float* bls   = (const float*)d_in[9];
    const float* wr    = (const float*)d_in[10];
    const float* bn2g  = (const float*)d_in[11];
    const float* bn2b  = (const float*)d_in[12];
    const float* wg    = (const float*)d_in[13];
    const float* bg    = (const float*)d_in[14];

    const int N = in_sizes[0] / H;
    const int E = in_sizes[1] / 2;
    const int* src = ei;
    const int* dst = ei + E;
    float* outp = (float*)d_out;

    // workspace layout (all 16B-aligned)
    float* B0   = (float*)d_ws;                 // N*H floats
    float* B1   = B0 + (size_t)N * H;           // N*H floats
    float* dinv = B1 + (size_t)N * H;           // N floats
    float* st   = dinv + N;                     // 1024 floats
    int*  deg   = (int*)(st + 1024);            // N ints
    int*  cursor= deg + N;                      // N ints
    int*  bsum  = cursor + N;                   // 1024 ints
    int*  csr   = bsum + 1024;                  // E ints
    float* sum1 = st,        *sumsq1 = st + 128;
    float* sum2 = st + 256,  *sumsq2 = st + 384;
    float* scale1 = st + 512, *shift1 = st + 640;
    float* scale2 = st + 768, *shift2 = st + 896;

    hipMemsetAsync(deg, 0, (size_t)N * sizeof(int), stream);
    hipMemsetAsync(st, 0, 1024 * sizeof(float), stream);

    const int eblk = (E + 255) / 256;
    const int nb = (N + 1023) / 1024;

    // ---- CSR build ----
    k_hist<<<eblk, 256, 0, stream>>>(dst, deg, E);
    k_scan1<<<nb, 256, 0, stream>>>(deg, cursor, bsum, N);
    k_scan2<<<1, 256, 0, stream>>>(bsum, nb);
    k_scan3<<<(N + 255) / 256, 256, 0, stream>>>(cursor, bsum, N);
    k_fill<<<eblk, 256, 0, stream>>>(src, dst, cursor, csr, E);
    k_dinv<<<(N + 255) / 256, 256, 0, stream>>>(deg, dinv, N);

    const int aggblk = (N * 64 + 255) / 256;   // wave per row
    const int gblocks = (N + 63) / 64;

    // ---- layer 1 ----
    k_agg1<<<aggblk, 256, 0, stream>>>(x, csr, cursor, deg, B0, N);
    k_gemm_lin1<<<gblocks, 256, 0, stream>>>(B0, w1, b1, B1, N);
    k_gemm_lin2norm<<<gblocks, 256, 0, stream>>>(B1, w2, b2, B0, sum1, sumsq1, N);
    k_bnparams<<<1, 128, 0, stream>>>(sum1, sumsq1, bn1g, bn1b, scale1, shift1, 1.0f / N);

    // ---- layer 2 ----
    k_agg2<<<aggblk, 256, 0, stream>>>(B0, scale1, shift1, csr, cursor, deg, B1, N);
    k_gemm_sage<<<gblocks, 256, 0, stream>>>(B1, B0, scale1, shift1,
                                             wl, bls, wr, B1, sum2, sumsq2, N);
    k_bnparams<<<1, 128, 0, stream>>>(sum2, sumsq2, bn2g, bn2b, scale2, shift2, 1.0f / N);

    // ---- layer 3 ----
    k_gcn<<<(N + 31) / 32, 320, 0, stream>>>(B1, scale2, shift2, wg, dinv, B0, N);
    k_agg3<<<aggblk, 256, 0, stream>>>(B0, dinv, csr, cursor, deg, bg, outp, N);
}